// Round 6
// baseline (766.268 us; speedup 1.0000x reference)
//
#include <hip/hip_runtime.h>
#include <hip/hip_bf16.h>

// ---------------------------------------------------------------------------
// DeepSGC on MI355X:
//   - CSR build per call: rank-recording deg pass, 2-kernel scan, atomic-free fill
//   - hop pairs folded: k1: z = N^2 A (N.x via gather-scale); k2: y = N A z
//   - 128-wide SpMM: half-wave float4 gather, 8-edge unroll, tail clamped to
//     end-1 (same-line reuse), nontemporal output stores (preserve L2 for gather)
//   - 40-wide SpMM: 6 edge-slots x 10 lanes x float4, 18-edge unroll, same fixes
//   - dense layers via 3x bf16 MFMA split-precision (hi+lo)
//   - layer-3 reorder: project 128->40 first, then 2 hops at 40-wide
// ---------------------------------------------------------------------------

typedef __attribute__((ext_vector_type(8))) short short8v;   // 8 x bf16
typedef __attribute__((ext_vector_type(4))) float f32x4;
typedef __attribute__((ext_vector_type(2))) unsigned int u32x2;

#define SBLK 128  // scan segments

__device__ __forceinline__ unsigned short f2bf(float x) {
    unsigned int u = __builtin_bit_cast(unsigned int, x);
    unsigned int r = u + 0x7fffu + ((u >> 16) & 1u);   // RNE
    return (unsigned short)(r >> 16);
}
__device__ __forceinline__ float bf2f(unsigned short h) {
    unsigned int u = ((unsigned int)h) << 16;
    return __builtin_bit_cast(float, u);
}

// ------------------------------- CSR build --------------------------------

// One thread per edge: histogram + per-edge arrival rank (atomic-free fill later).
__global__ void __launch_bounds__(256) deg_rank_kernel(const int* __restrict__ dst,
                                                       int* __restrict__ deg,
                                                       int* __restrict__ rank, int E) {
    int e = blockIdx.x * blockDim.x + threadIdx.x;
    if (e < E) rank[e] = atomicAdd(&deg[dst[e]], 1);
}

// Per-segment exclusive scan + segment totals + norm computation.
__global__ void __launch_bounds__(256) scanA_kernel(const int* __restrict__ deg,
                                                    int* __restrict__ rowptr,
                                                    int* __restrict__ bsum,
                                                    float* __restrict__ norm,
                                                    int n, int seg) {
    __shared__ int ws[4];
    __shared__ int carry;
    int b = blockIdx.x;
    int start = b * seg;
    int finish = start + seg; if (finish > n) finish = n;
    int t = threadIdx.x, lane = t & 63, w = t >> 6;
    if (t == 0) carry = 0;
    __syncthreads();
    for (int base = start; base < finish; base += 256) {
        int i = base + t;
        int v = 0;
        if (i < finish) {
            v = deg[i];
            norm[i] = rsqrtf((float)(v < 1 ? 1 : v));
        }
        int x = v;
        #pragma unroll
        for (int off = 1; off < 64; off <<= 1) {
            int y = __shfl_up(x, off, 64);
            if (lane >= off) x += y;
        }
        if (lane == 63) ws[w] = x;
        __syncthreads();
        int woff = 0;
        #pragma unroll
        for (int k = 0; k < 4; ++k) if (k < w) woff += ws[k];
        if (i < finish) rowptr[i] = carry + woff + x - v;
        int tot = ws[0] + ws[1] + ws[2] + ws[3];
        __syncthreads();
        if (t == 0) carry += tot;
        __syncthreads();
    }
    if (t == 0) bsum[b] = carry;
}

// Fused: every block redundantly scans the SBLK segment totals in LDS,
// then adds its segment offset. Block 0 writes rowptr[n].
__global__ void __launch_bounds__(256) scanC_kernel(int* __restrict__ rowptr,
                                                    const int* __restrict__ bsum,
                                                    int n, int seg) {
    __shared__ int tmp[SBLK + 1];
    int b = blockIdx.x, t = threadIdx.x;
    if (t < SBLK) tmp[t] = bsum[t];
    __syncthreads();
    if (t == 0) {
        int s = 0;
        #pragma unroll 4
        for (int i = 0; i < SBLK; ++i) { int v = tmp[i]; tmp[i] = s; s += v; }
        tmp[SBLK] = s;
    }
    __syncthreads();
    int add = tmp[b];
    int start = b * seg;
    int finish = start + seg; if (finish > n) finish = n;
    for (int i = start + t; i < finish; i += 256) rowptr[i] += add;
    if (b == 0 && t == 0) rowptr[n] = tmp[SBLK];
}

// Atomic-free fill: one thread per edge, position known from rank.
__global__ void __launch_bounds__(256) fill_kernel(const int* __restrict__ src,
                                                   const int* __restrict__ dst,
                                                   const int* __restrict__ rowptr,
                                                   const int* __restrict__ rank,
                                                   int* __restrict__ col, int E) {
    int e = blockIdx.x * blockDim.x + threadIdx.x;
    if (e < E) col[rowptr[dst[e]] + rank[e]] = src[e];
}

// ------------------------------- SpMM hops --------------------------------
// Half-wave float4 gather: lanes 0-31 handle even edges, 32-63 odd edges.
// Eight edges in flight per iteration. Tail slots clamp to end-1 so the
// redundant load duplicates a row fetched by a valid slot in the SAME
// iteration (L1-line reuse instead of a cold re-fetch of col[beg]).

// k1 of a pair: z = N^2 * A * (N . x)   (gather-scale by norm[src], f32 out)
__global__ void __launch_bounds__(256) spmm128_a(const float4* __restrict__ hin,
                                                 f32x4* __restrict__ hout,
                                                 const int* __restrict__ rp,
                                                 const int* __restrict__ col,
                                                 const float* __restrict__ norm,
                                                 int n) {
    int wid = (blockIdx.x * blockDim.x + threadIdx.x) >> 6;
    if (wid >= n) return;
    int lane = threadIdx.x & 63, half = lane >> 5, l32 = lane & 31;
    int beg = rp[wid], end = rp[wid + 1];
    f32x4 acc = {0.f, 0.f, 0.f, 0.f};
    if (beg < end) {
        int last = end - 1;
        for (int e = beg; e < end; e += 8) {
            int i0 = e + half, i1 = e + 2 + half, i2 = e + 4 + half, i3 = e + 6 + half;
            int i0c = i0 < end ? i0 : last;
            int i1c = i1 < end ? i1 : last;
            int i2c = i2 < end ? i2 : last;
            int i3c = i3 < end ? i3 : last;
            int u0 = col[i0c], u1 = col[i1c], u2 = col[i2c], u3 = col[i3c];
            float s0 = i0 < end ? norm[u0] : 0.f;
            float s1 = i1 < end ? norm[u1] : 0.f;
            float s2 = i2 < end ? norm[u2] : 0.f;
            float s3 = i3 < end ? norm[u3] : 0.f;
            float4 x0 = hin[(size_t)u0 * 32 + l32];
            float4 x1 = hin[(size_t)u1 * 32 + l32];
            float4 x2 = hin[(size_t)u2 * 32 + l32];
            float4 x3 = hin[(size_t)u3 * 32 + l32];
            acc.x += x0.x * s0; acc.y += x0.y * s0; acc.z += x0.z * s0; acc.w += x0.w * s0;
            acc.x += x1.x * s1; acc.y += x1.y * s1; acc.z += x1.z * s1; acc.w += x1.w * s1;
            acc.x += x2.x * s2; acc.y += x2.y * s2; acc.z += x2.z * s2; acc.w += x2.w * s2;
            acc.x += x3.x * s3; acc.y += x3.y * s3; acc.z += x3.z * s3; acc.w += x3.w * s3;
        }
    }
    acc.x += __shfl_xor(acc.x, 32);
    acc.y += __shfl_xor(acc.y, 32);
    acc.z += __shfl_xor(acc.z, 32);
    acc.w += __shfl_xor(acc.w, 32);
    if (half == 0) {
        float nv = norm[wid];
        float f = nv * nv;
        f32x4 o = {acc.x * f, acc.y * f, acc.z * f, acc.w * f};
        __builtin_nontemporal_store(o, &hout[(size_t)wid * 32 + l32]);
    }
}

// k2 of a pair: y = N * A * z  (no gather scale), emit split bf16 (hi+lo).
__global__ void __launch_bounds__(256) spmm128_b_split(const float4* __restrict__ hin,
                                                       u32x2* __restrict__ Hi,
                                                       u32x2* __restrict__ Lo,
                                                       const int* __restrict__ rp,
                                                       const int* __restrict__ col,
                                                       const float* __restrict__ norm,
                                                       int n) {
    int wid = (blockIdx.x * blockDim.x + threadIdx.x) >> 6;
    if (wid >= n) return;
    int lane = threadIdx.x & 63, half = lane >> 5, l32 = lane & 31;
    int beg = rp[wid], end = rp[wid + 1];
    f32x4 acc = {0.f, 0.f, 0.f, 0.f};
    if (beg < end) {
        int last = end - 1;
        for (int e = beg; e < end; e += 8) {
            int i0 = e + half, i1 = e + 2 + half, i2 = e + 4 + half, i3 = e + 6 + half;
            int i0c = i0 < end ? i0 : last;
            int i1c = i1 < end ? i1 : last;
            int i2c = i2 < end ? i2 : last;
            int i3c = i3 < end ? i3 : last;
            int u0 = col[i0c], u1 = col[i1c], u2 = col[i2c], u3 = col[i3c];
            float s0 = i0 < end ? 1.f : 0.f;
            float s1 = i1 < end ? 1.f : 0.f;
            float s2 = i2 < end ? 1.f : 0.f;
            float s3 = i3 < end ? 1.f : 0.f;
            float4 x0 = hin[(size_t)u0 * 32 + l32];
            float4 x1 = hin[(size_t)u1 * 32 + l32];
            float4 x2 = hin[(size_t)u2 * 32 + l32];
            float4 x3 = hin[(size_t)u3 * 32 + l32];
            acc.x += x0.x * s0; acc.y += x0.y * s0; acc.z += x0.z * s0; acc.w += x0.w * s0;
            acc.x += x1.x * s1; acc.y += x1.y * s1; acc.z += x1.z * s1; acc.w += x1.w * s1;
            acc.x += x2.x * s2; acc.y += x2.y * s2; acc.z += x2.z * s2; acc.w += x2.w * s2;
            acc.x += x3.x * s3; acc.y += x3.y * s3; acc.z += x3.z * s3; acc.w += x3.w * s3;
        }
    }
    acc.x += __shfl_xor(acc.x, 32);
    acc.y += __shfl_xor(acc.y, 32);
    acc.z += __shfl_xor(acc.z, 32);
    acc.w += __shfl_xor(acc.w, 32);
    if (half == 0) {
        float nv = norm[wid];
        float v0 = acc.x * nv, v1 = acc.y * nv, v2 = acc.z * nv, v3 = acc.w * nv;
        unsigned short h0 = f2bf(v0), h1 = f2bf(v1), h2 = f2bf(v2), h3 = f2bf(v3);
        unsigned short l0 = f2bf(v0 - bf2f(h0)), l1 = f2bf(v1 - bf2f(h1));
        unsigned short l2 = f2bf(v2 - bf2f(h2)), l3 = f2bf(v3 - bf2f(h3));
        u32x2 hp = {(unsigned int)h0 | ((unsigned int)h1 << 16),
                    (unsigned int)h2 | ((unsigned int)h3 << 16)};
        u32x2 lp = {(unsigned int)l0 | ((unsigned int)l1 << 16),
                    (unsigned int)l2 | ((unsigned int)l3 << 16)};
        __builtin_nontemporal_store(hp, &Hi[(size_t)wid * 32 + l32]);
        __builtin_nontemporal_store(lp, &Lo[(size_t)wid * 32 + l32]);
    }
}

// 40-wide hops: 6 edge-slots x 10 lanes, each slot gathers a row as float4.
// Unroll 3 -> 18 edges in flight. Cross-slot reduce via shfl.
template <int FIRST, int BIAS>
__global__ void __launch_bounds__(256) spmm40_kernel(const f32x4* __restrict__ hin,
                                                     f32x4* __restrict__ hout,
                                                     const int* __restrict__ rp,
                                                     const int* __restrict__ col,
                                                     const float* __restrict__ norm,
                                                     const float* __restrict__ b3,
                                                     int n) {
    int wid = (blockIdx.x * blockDim.x + threadIdx.x) >> 6;
    if (wid >= n) return;
    int lane = threadIdx.x & 63;
    int slot = lane / 10;      // 0..5 active edge slots; lanes 60-63 idle
    int t = lane % 10;         // float4 index within the 40-float row
    bool active = slot < 6;
    int beg = rp[wid], end = rp[wid + 1];
    f32x4 acc = {0.f, 0.f, 0.f, 0.f};
    if (beg < end) {
        int last = end - 1;
        for (int base = beg; base < end; base += 18) {
            int i0 = base + slot, i1 = base + 6 + slot, i2 = base + 12 + slot;
            int i0c = (active && i0 < end) ? i0 : last;
            int i1c = (active && i1 < end) ? i1 : last;
            int i2c = (active && i2 < end) ? i2 : last;
            int u0 = col[i0c], u1 = col[i1c], u2 = col[i2c];
            float s0 = (active && i0 < end) ? (FIRST ? norm[u0] : 1.f) : 0.f;
            float s1 = (active && i1 < end) ? (FIRST ? norm[u1] : 1.f) : 0.f;
            float s2 = (active && i2 < end) ? (FIRST ? norm[u2] : 1.f) : 0.f;
            f32x4 x0 = hin[(size_t)u0 * 10 + t];
            f32x4 x1 = hin[(size_t)u1 * 10 + t];
            f32x4 x2 = hin[(size_t)u2 * 10 + t];
            acc.x += x0.x * s0; acc.y += x0.y * s0; acc.z += x0.z * s0; acc.w += x0.w * s0;
            acc.x += x1.x * s1; acc.y += x1.y * s1; acc.z += x1.z * s1; acc.w += x1.w * s1;
            acc.x += x2.x * s2; acc.y += x2.y * s2; acc.z += x2.z * s2; acc.w += x2.w * s2;
        }
    }
    // total over the 6 slots (read the UNMODIFIED acc; all lanes participate)
    f32x4 tot = acc;
    #pragma unroll
    for (int k = 1; k < 6; ++k) {
        int srcl = (lane % 10) + ((slot + k) % 6) * 10;  // < 60, always valid
        tot.x += __shfl(acc.x, srcl);
        tot.y += __shfl(acc.y, srcl);
        tot.z += __shfl(acc.z, srcl);
        tot.w += __shfl(acc.w, srcl);
    }
    if (slot == 0) {  // lanes 0-9 write the 40-float row
        float nv = norm[wid];
        float f = FIRST ? nv * nv : nv;
        f32x4 o = {tot.x * f, tot.y * f, tot.z * f, tot.w * f};
        if (BIAS) {
            f32x4 bv = ((const f32x4*)b3)[t];
            o.x += bv.x; o.y += bv.y; o.z += bv.z; o.w += bv.w;
        }
        __builtin_nontemporal_store(o, &hout[(size_t)wid * 10 + t]);
    }
}

// ------------------------- W fragment preparation --------------------------
// frag f = ks*CF + cf; element (f, lane, j) = W[k][c],
// k = ks*32 + 8*(lane>>4) + j, c = cf*16 + (lane&15).

__device__ __forceinline__ void wprep_one(const float* __restrict__ W,
                                          short* __restrict__ Wh,
                                          short* __restrict__ Wl,
                                          int ncols, int CF, int i) {
    int j = i & 7;
    int lane = (i >> 3) & 63;
    int f = i >> 9;
    int cf = f % CF, ks = f / CF;
    int k = ks * 32 + 8 * (lane >> 4) + j;
    int c = cf * 16 + (lane & 15);
    float v = (c < ncols) ? W[k * ncols + c] : 0.f;
    unsigned short h = f2bf(v);
    unsigned short l = f2bf(v - bf2f(h));
    Wh[i] = (short)h;
    Wl[i] = (short)l;
}

__global__ void __launch_bounds__(256) wprep_all(const float* __restrict__ W1,
                                                 const float* __restrict__ W2,
                                                 const float* __restrict__ W3,
                                                 short* __restrict__ W1h, short* __restrict__ W1l,
                                                 short* __restrict__ W2h, short* __restrict__ W2l,
                                                 short* __restrict__ W3h, short* __restrict__ W3l) {
    int i = blockIdx.x * blockDim.x + threadIdx.x;
    if (i < 16384) wprep_one(W1, W1h, W1l, 128, 8, i);
    else if (i < 32768) wprep_one(W2, W2h, W2l, 128, 8, i - 16384);
    else if (i < 38912) wprep_one(W3, W3h, W3l, 40, 3, i - 32768);
}

// ------------------------- split-bf16 MFMA GEMMs ---------------------------

template <int MODE>  // 0: f32 out (+bias+relu), 1: split-bf16 out (+bias+relu)
__global__ void __launch_bounds__(256) gemm_mfma128(const unsigned short* __restrict__ Ahi,
                                                    const unsigned short* __restrict__ Alo,
                                                    const short8v* __restrict__ Wh,
                                                    const short8v* __restrict__ Wl,
                                                    const float* __restrict__ bias,
                                                    float* __restrict__ Cf,
                                                    unsigned short* __restrict__ Chi,
                                                    unsigned short* __restrict__ Clo,
                                                    int n) {
    int lane = threadIdx.x & 63;
    int wid = threadIdx.x >> 6;
    int r0 = blockIdx.x * 64 + wid * 16;
    if (r0 >= n) return;
    int arow = r0 + (lane & 15);
    if (arow > n - 1) arow = n - 1;
    int kbase = 8 * (lane >> 4);
    f32x4 acc[8];
    #pragma unroll
    for (int i = 0; i < 8; ++i) acc[i] = (f32x4){0.f, 0.f, 0.f, 0.f};
    #pragma unroll
    for (int ks = 0; ks < 4; ++ks) {
        short8v ah = *(const short8v*)(Ahi + (size_t)arow * 128 + ks * 32 + kbase);
        short8v al = *(const short8v*)(Alo + (size_t)arow * 128 + ks * 32 + kbase);
        #pragma unroll
        for (int cf = 0; cf < 8; ++cf) {
            short8v bh = Wh[(ks * 8 + cf) * 64 + lane];
            short8v bl = Wl[(ks * 8 + cf) * 64 + lane];
            acc[cf] = __builtin_amdgcn_mfma_f32_16x16x32_bf16(ah, bh, acc[cf], 0, 0, 0);
            acc[cf] = __builtin_amdgcn_mfma_f32_16x16x32_bf16(al, bh, acc[cf], 0, 0, 0);
            acc[cf] = __builtin_amdgcn_mfma_f32_16x16x32_bf16(ah, bl, acc[cf], 0, 0, 0);
        }
    }
    int rbase = r0 + (lane >> 4) * 4;
    int c0 = lane & 15;
    #pragma unroll
    for (int cf = 0; cf < 8; ++cf) {
        int colc = cf * 16 + c0;
        float b = bias[colc];
        #pragma unroll
        for (int q = 0; q < 4; ++q) {
            int row = rbase + q;
            if (row >= n) continue;
            float v = fmaxf(acc[cf][q] + b, 0.f);
            if (MODE == 0) {
                Cf[(size_t)row * 128 + colc] = v;
            } else {
                unsigned short h = f2bf(v);
                unsigned short l = f2bf(v - bf2f(h));
                Chi[(size_t)row * 128 + colc] = h;
                Clo[(size_t)row * 128 + colc] = l;
            }
        }
    }
}

__global__ void __launch_bounds__(256) gemm_mfma40(const unsigned short* __restrict__ Ahi,
                                                   const unsigned short* __restrict__ Alo,
                                                   const short8v* __restrict__ Wh,
                                                   const short8v* __restrict__ Wl,
                                                   float* __restrict__ Cf, int n) {
    int lane = threadIdx.x & 63;
    int wid = threadIdx.x >> 6;
    int r0 = blockIdx.x * 64 + wid * 16;
    if (r0 >= n) return;
    int arow = r0 + (lane & 15);
    if (arow > n - 1) arow = n - 1;
    int kbase = 8 * (lane >> 4);
    f32x4 acc[3];
    #pragma unroll
    for (int i = 0; i < 3; ++i) acc[i] = (f32x4){0.f, 0.f, 0.f, 0.f};
    #pragma unroll
    for (int ks = 0; ks < 4; ++ks) {
        short8v ah = *(const short8v*)(Ahi + (size_t)arow * 128 + ks * 32 + kbase);
        short8v al = *(const short8v*)(Alo + (size_t)arow * 128 + ks * 32 + kbase);
        #pragma unroll
        for (int cf = 0; cf < 3; ++cf) {
            short8v bh = Wh[(ks * 3 + cf) * 64 + lane];
            short8v bl = Wl[(ks * 3 + cf) * 64 + lane];
            acc[cf] = __builtin_amdgcn_mfma_f32_16x16x32_bf16(ah, bh, acc[cf], 0, 0, 0);
            acc[cf] = __builtin_amdgcn_mfma_f32_16x16x32_bf16(al, bh, acc[cf], 0, 0, 0);
            acc[cf] = __builtin_amdgcn_mfma_f32_16x16x32_bf16(ah, bl, acc[cf], 0, 0, 0);
        }
    }
    int rbase = r0 + (lane >> 4) * 4;
    int c0 = lane & 15;
    #pragma unroll
    for (int cf = 0; cf < 3; ++cf) {
        int colc = cf * 16 + c0;
        if (colc >= 40) continue;
        #pragma unroll
        for (int q = 0; q < 4; ++q) {
            int row = rbase + q;
            if (row >= n) continue;
            Cf[(size_t)row * 40 + colc] = acc[cf][q];
        }
    }
}

// --------------------------------- launch ----------------------------------

extern "C" void kernel_launch(void* const* d_in, const int* in_sizes, int n_in,
                              void* d_out, int out_size, void* d_ws, size_t ws_size,
                              hipStream_t stream) {
    const float* features = (const float*)d_in[0];
    const int*   src      = (const int*)d_in[1];
    const int*   dst      = (const int*)d_in[2];
    const float* W1 = (const float*)d_in[3];
    const float* b1 = (const float*)d_in[4];
    const float* W2 = (const float*)d_in[5];
    const float* b2 = (const float*)d_in[6];
    const float* W3 = (const float*)d_in[7];
    const float* b3 = (const float*)d_in[8];
    float* out = (float*)d_out;

    const int N = in_sizes[0] / 128;
    const int E = in_sizes[1];

    char* ws = (char*)d_ws;
    size_t off = 0;
    auto alloc = [&](size_t bytes) -> void* {
        void* p = ws + off;
        off += (bytes + 511) & ~(size_t)511;
        return p;
    };
    float*          F1   = (float*)alloc((size_t)N * 128 * sizeof(float));
    float*          F2   = (float*)alloc((size_t)N * 128 * sizeof(float));
    unsigned short* Hi   = (unsigned short*)alloc((size_t)N * 128 * sizeof(unsigned short));
    unsigned short* Lo   = (unsigned short*)alloc((size_t)N * 128 * sizeof(unsigned short));
    int*   col    = (int*)alloc((size_t)E * sizeof(int));
    int*   deg    = (int*)alloc((size_t)N * sizeof(int));
    int*   rowptr = (int*)alloc((size_t)(N + 1) * sizeof(int));
    float* norm   = (float*)alloc((size_t)N * sizeof(float));
    int*   bsum   = (int*)alloc((size_t)(SBLK + 2) * sizeof(int));
    short* W1h = (short*)alloc(16384 * sizeof(short));
    short* W1l = (short*)alloc(16384 * sizeof(short));
    short* W2h = (short*)alloc(16384 * sizeof(short));
    short* W2l = (short*)alloc(16384 * sizeof(short));
    short* W3h = (short*)alloc(6144 * sizeof(short));
    short* W3l = (short*)alloc(6144 * sizeof(short));
    // rank aliases F1 (dead until spmm128_a writes it, after fill consumed rank)
    int* rank = (int*)F1;
    // 40-wide hop buffers alias F2 (dead after hop 3 consumed it)
    float* G40a = (float*)F2;
    float* G40b = (float*)F2 + (size_t)N * 40;

    const int seg = (N + SBLK - 1) / SBLK;
    const int eblocks = (E + 255) / 256;

    // --- CSR build ---
    hipMemsetAsync(deg, 0, (size_t)N * sizeof(int), stream);
    deg_rank_kernel<<<eblocks, 256, 0, stream>>>(dst, deg, rank, E);
    scanA_kernel<<<SBLK, 256, 0, stream>>>(deg, rowptr, bsum, norm, N, seg);
    scanC_kernel<<<SBLK, 256, 0, stream>>>(rowptr, bsum, N, seg);
    fill_kernel<<<eblocks, 256, 0, stream>>>(src, dst, rowptr, rank, col, E);

    // --- W fragment prep (one launch for all three) ---
    wprep_all<<<(38912 + 255) / 256, 256, 0, stream>>>(W1, W2, W3, W1h, W1l, W2h, W2l, W3h, W3l);

    const int spmm_blocks = (N * 64 + 255) / 256;  // one wave per node
    const int gemm_blocks = (N + 63) / 64;

    // layer 1: z = N^2 A N x ; y = N A z ; relu(y W1 + b1)
    spmm128_a<<<spmm_blocks, 256, 0, stream>>>((const float4*)features, (f32x4*)F1, rowptr, col, norm, N);
    spmm128_b_split<<<spmm_blocks, 256, 0, stream>>>((const float4*)F1, (u32x2*)Hi, (u32x2*)Lo, rowptr, col, norm, N);
    gemm_mfma128<0><<<gemm_blocks, 256, 0, stream>>>(Hi, Lo, (const short8v*)W1h, (const short8v*)W1l, b1, F2, nullptr, nullptr, N);

    // layer 2
    spmm128_a<<<spmm_blocks, 256, 0, stream>>>((const float4*)F2, (f32x4*)F1, rowptr, col, norm, N);
    spmm128_b_split<<<spmm_blocks, 256, 0, stream>>>((const float4*)F1, (u32x2*)Hi, (u32x2*)Lo, rowptr, col, norm, N);
    gemm_mfma128<1><<<gemm_blocks, 256, 0, stream>>>(Hi, Lo, (const short8v*)W2h, (const short8v*)W2l, b2, nullptr, Hi, Lo, N);

    // layer 3 (reordered): project 128->40 first, then 2 hops at 40-wide, + b3
    gemm_mfma40<<<gemm_blocks, 256, 0, stream>>>(Hi, Lo, (const short8v*)W3h, (const short8v*)W3l, G40a, N);
    spmm40_kernel<1, 0><<<spmm_blocks, 256, 0, stream>>>((const f32x4*)G40a, (f32x4*)G40b, rowptr, col, norm, nullptr, N);
    spmm40_kernel<0, 1><<<spmm_blocks, 256, 0, stream>>>((const f32x4*)G40b, (f32x4*)out, rowptr, col, norm, b3, N);
}

// Round 7
// 639.562 us; speedup vs baseline: 1.1981x; 1.1981x over previous
//
#include <hip/hip_runtime.h>
#include <hip/hip_bf16.h>

// ---------------------------------------------------------------------------
// DeepSGC on MI355X:
//   - CSR build per call: rank-recording deg pass, 2-kernel scan, atomic-free fill
//   - 128-wide hops gather INT16 row-quantized features (256B/row vs 512B):
//     per-row scale S (dequant) and Sn = S*norm (fuses the norm gather-scale).
//     Error <= rowmax*2^-16 per quantization -- 4 quant points, ~4e-4 total.
//   - hop pairs folded: k1: z = N^2 A (Sn-scaled gather); k2: y = N A z
//   - dense layers via 3x bf16 MFMA split-precision (hi+lo), exact vs fp32
//   - layer-3 reorder: project 128->40 first, then 2 hops at 40-wide (f32)
// ---------------------------------------------------------------------------

typedef __attribute__((ext_vector_type(8))) short short8v;   // 8 x bf16
typedef __attribute__((ext_vector_type(4))) float f32x4;
typedef __attribute__((ext_vector_type(2))) unsigned int u32x2;

#define SBLK 128  // scan segments

__device__ __forceinline__ unsigned short f2bf(float x) {
    unsigned int u = __builtin_bit_cast(unsigned int, x);
    unsigned int r = u + 0x7fffu + ((u >> 16) & 1u);   // RNE
    return (unsigned short)(r >> 16);
}
__device__ __forceinline__ float bf2f(unsigned short h) {
    unsigned int u = ((unsigned int)h) << 16;
    return __builtin_bit_cast(float, u);
}

// ------------------------------- CSR build --------------------------------

__global__ void __launch_bounds__(256) deg_rank_kernel(const int* __restrict__ dst,
                                                       int* __restrict__ deg,
                                                       int* __restrict__ rank, int E) {
    int e = blockIdx.x * blockDim.x + threadIdx.x;
    if (e < E) rank[e] = atomicAdd(&deg[dst[e]], 1);
}

__global__ void __launch_bounds__(256) scanA_kernel(const int* __restrict__ deg,
                                                    int* __restrict__ rowptr,
                                                    int* __restrict__ bsum,
                                                    float* __restrict__ norm,
                                                    int n, int seg) {
    __shared__ int ws[4];
    __shared__ int carry;
    int b = blockIdx.x;
    int start = b * seg;
    int finish = start + seg; if (finish > n) finish = n;
    int t = threadIdx.x, lane = t & 63, w = t >> 6;
    if (t == 0) carry = 0;
    __syncthreads();
    for (int base = start; base < finish; base += 256) {
        int i = base + t;
        int v = 0;
        if (i < finish) {
            v = deg[i];
            norm[i] = rsqrtf((float)(v < 1 ? 1 : v));
        }
        int x = v;
        #pragma unroll
        for (int off = 1; off < 64; off <<= 1) {
            int y = __shfl_up(x, off, 64);
            if (lane >= off) x += y;
        }
        if (lane == 63) ws[w] = x;
        __syncthreads();
        int woff = 0;
        #pragma unroll
        for (int k = 0; k < 4; ++k) if (k < w) woff += ws[k];
        if (i < finish) rowptr[i] = carry + woff + x - v;
        int tot = ws[0] + ws[1] + ws[2] + ws[3];
        __syncthreads();
        if (t == 0) carry += tot;
        __syncthreads();
    }
    if (t == 0) bsum[b] = carry;
}

__global__ void __launch_bounds__(256) scanC_kernel(int* __restrict__ rowptr,
                                                    const int* __restrict__ bsum,
                                                    int n, int seg) {
    __shared__ int tmp[SBLK + 1];
    int b = blockIdx.x, t = threadIdx.x;
    if (t < SBLK) tmp[t] = bsum[t];
    __syncthreads();
    if (t == 0) {
        int s = 0;
        #pragma unroll 4
        for (int i = 0; i < SBLK; ++i) { int v = tmp[i]; tmp[i] = s; s += v; }
        tmp[SBLK] = s;
    }
    __syncthreads();
    int add = tmp[b];
    int start = b * seg;
    int finish = start + seg; if (finish > n) finish = n;
    for (int i = start + t; i < finish; i += 256) rowptr[i] += add;
    if (b == 0 && t == 0) rowptr[n] = tmp[SBLK];
}

__global__ void __launch_bounds__(256) fill_kernel(const int* __restrict__ src,
                                                   const int* __restrict__ dst,
                                                   const int* __restrict__ rowptr,
                                                   const int* __restrict__ rank,
                                                   int* __restrict__ col, int E) {
    int e = blockIdx.x * blockDim.x + threadIdx.x;
    if (e < E) col[rowptr[dst[e]] + rank[e]] = src[e];
}

// ------------------------ input row quantization ---------------------------
// 2 nodes per wave (halves independent). Row of 128 f32 -> 128 int16 + scale.

__global__ void __launch_bounds__(256) xquant_kernel(const float4* __restrict__ x,
                                                     const float* __restrict__ norm,
                                                     u32x2* __restrict__ xq,
                                                     float* __restrict__ S,
                                                     float* __restrict__ Sn,
                                                     int n) {
    int gw = (blockIdx.x * blockDim.x + threadIdx.x) >> 6;
    int lane = threadIdx.x & 63, half = lane >> 5, l32 = lane & 31;
    int node = gw * 2 + half;
    if (node >= n) return;
    float4 v = x[(size_t)node * 32 + l32];
    float m = fmaxf(fmaxf(fabsf(v.x), fabsf(v.y)), fmaxf(fabsf(v.z), fabsf(v.w)));
    #pragma unroll
    for (int s = 1; s < 32; s <<= 1) m = fmaxf(m, __shfl_xor(m, s));
    float sraw = fmaxf(m, 1e-30f);
    float inv = 32767.f / sraw;
    float sv = sraw * (1.f / 32767.f);
    int a0 = (int)rintf(fminf(fmaxf(v.x * inv, -32767.f), 32767.f));
    int a1 = (int)rintf(fminf(fmaxf(v.y * inv, -32767.f), 32767.f));
    int a2 = (int)rintf(fminf(fmaxf(v.z * inv, -32767.f), 32767.f));
    int a3 = (int)rintf(fminf(fmaxf(v.w * inv, -32767.f), 32767.f));
    u32x2 p = {(unsigned)(a0 & 0xffff) | ((unsigned)a1 << 16),
               (unsigned)(a2 & 0xffff) | ((unsigned)a3 << 16)};
    __builtin_nontemporal_store(p, &xq[(size_t)node * 32 + l32]);
    if (l32 == 0) { S[node] = sv; Sn[node] = sv * norm[node]; }
}

// ------------------------------- SpMM hops --------------------------------
// Quantized gather: row = 128 int16 = 32 x u32x2 (8 B/lane, half-wave/row).
// esc[u] = Sn[u] for k1 (fuses norm), S[u] for k2. 8 edges in flight/iter.

template <int EPI>  // 0: quantize out (+S/Sn) [k1]; 1: Hi/Lo bf16 split out [k2]
__global__ void __launch_bounds__(256) spmm128_q(const u32x2* __restrict__ hq,
                                                 const float* __restrict__ esc,
                                                 const int* __restrict__ rp,
                                                 const int* __restrict__ col,
                                                 const float* __restrict__ norm,
                                                 u32x2* __restrict__ outq,
                                                 float* __restrict__ So,
                                                 float* __restrict__ Sno,
                                                 u32x2* __restrict__ Hi,
                                                 u32x2* __restrict__ Lo,
                                                 int n) {
    int wid = (blockIdx.x * blockDim.x + threadIdx.x) >> 6;
    if (wid >= n) return;
    int lane = threadIdx.x & 63, half = lane >> 5, l32 = lane & 31;
    int beg = rp[wid], end = rp[wid + 1];
    f32x4 acc = {0.f, 0.f, 0.f, 0.f};
    if (beg < end) {
        int last = end - 1;
        for (int e = beg; e < end; e += 8) {
            int i0 = e + half, i1 = e + 2 + half, i2 = e + 4 + half, i3 = e + 6 + half;
            int i0c = i0 < end ? i0 : last;
            int i1c = i1 < end ? i1 : last;
            int i2c = i2 < end ? i2 : last;
            int i3c = i3 < end ? i3 : last;
            int u0 = col[i0c], u1 = col[i1c], u2 = col[i2c], u3 = col[i3c];
            float s0 = i0 < end ? esc[u0] : 0.f;
            float s1 = i1 < end ? esc[u1] : 0.f;
            float s2 = i2 < end ? esc[u2] : 0.f;
            float s3 = i3 < end ? esc[u3] : 0.f;
            u32x2 q0 = hq[(size_t)u0 * 32 + l32];
            u32x2 q1 = hq[(size_t)u1 * 32 + l32];
            u32x2 q2 = hq[(size_t)u2 * 32 + l32];
            u32x2 q3 = hq[(size_t)u3 * 32 + l32];
            acc.x += (float)(short)(q0.x) * s0;
            acc.y += (float)((int)q0.x >> 16) * s0;
            acc.z += (float)(short)(q0.y) * s0;
            acc.w += (float)((int)q0.y >> 16) * s0;
            acc.x += (float)(short)(q1.x) * s1;
            acc.y += (float)((int)q1.x >> 16) * s1;
            acc.z += (float)(short)(q1.y) * s1;
            acc.w += (float)((int)q1.y >> 16) * s1;
            acc.x += (float)(short)(q2.x) * s2;
            acc.y += (float)((int)q2.x >> 16) * s2;
            acc.z += (float)(short)(q2.y) * s2;
            acc.w += (float)((int)q2.y >> 16) * s2;
            acc.x += (float)(short)(q3.x) * s3;
            acc.y += (float)((int)q3.x >> 16) * s3;
            acc.z += (float)(short)(q3.y) * s3;
            acc.w += (float)((int)q3.y >> 16) * s3;
        }
    }
    acc.x += __shfl_xor(acc.x, 32);
    acc.y += __shfl_xor(acc.y, 32);
    acc.z += __shfl_xor(acc.z, 32);
    acc.w += __shfl_xor(acc.w, 32);
    float nv = norm[wid];
    if (EPI == 0) {
        float f = nv * nv;
        acc.x *= f; acc.y *= f; acc.z *= f; acc.w *= f;
        float m = fmaxf(fmaxf(fabsf(acc.x), fabsf(acc.y)), fmaxf(fabsf(acc.z), fabsf(acc.w)));
        #pragma unroll
        for (int s = 1; s < 64; s <<= 1) m = fmaxf(m, __shfl_xor(m, s));
        float sraw = fmaxf(m, 1e-30f);
        float inv = 32767.f / sraw;
        float sv = sraw * (1.f / 32767.f);
        if (half == 0) {
            int a0 = (int)rintf(fminf(fmaxf(acc.x * inv, -32767.f), 32767.f));
            int a1 = (int)rintf(fminf(fmaxf(acc.y * inv, -32767.f), 32767.f));
            int a2 = (int)rintf(fminf(fmaxf(acc.z * inv, -32767.f), 32767.f));
            int a3 = (int)rintf(fminf(fmaxf(acc.w * inv, -32767.f), 32767.f));
            u32x2 p = {(unsigned)(a0 & 0xffff) | ((unsigned)a1 << 16),
                       (unsigned)(a2 & 0xffff) | ((unsigned)a3 << 16)};
            __builtin_nontemporal_store(p, &outq[(size_t)wid * 32 + l32]);
        }
        if (lane == 0) { So[wid] = sv; Sno[wid] = sv * nv; }
    } else {
        if (half == 0) {
            float v0 = acc.x * nv, v1 = acc.y * nv, v2 = acc.z * nv, v3 = acc.w * nv;
            unsigned short h0 = f2bf(v0), h1 = f2bf(v1), h2 = f2bf(v2), h3 = f2bf(v3);
            unsigned short l0 = f2bf(v0 - bf2f(h0)), l1 = f2bf(v1 - bf2f(h1));
            unsigned short l2 = f2bf(v2 - bf2f(h2)), l3 = f2bf(v3 - bf2f(h3));
            u32x2 hp = {(unsigned int)h0 | ((unsigned int)h1 << 16),
                        (unsigned int)h2 | ((unsigned int)h3 << 16)};
            u32x2 lp = {(unsigned int)l0 | ((unsigned int)l1 << 16),
                        (unsigned int)l2 | ((unsigned int)l3 << 16)};
            __builtin_nontemporal_store(hp, &Hi[(size_t)wid * 32 + l32]);
            __builtin_nontemporal_store(lp, &Lo[(size_t)wid * 32 + l32]);
        }
    }
}

// 40-wide hops (f32): 6 edge-slots x 10 lanes x float4, 18-edge unroll.
template <int FIRST, int BIAS>
__global__ void __launch_bounds__(256) spmm40_kernel(const f32x4* __restrict__ hin,
                                                     f32x4* __restrict__ hout,
                                                     const int* __restrict__ rp,
                                                     const int* __restrict__ col,
                                                     const float* __restrict__ norm,
                                                     const float* __restrict__ b3,
                                                     int n) {
    int wid = (blockIdx.x * blockDim.x + threadIdx.x) >> 6;
    if (wid >= n) return;
    int lane = threadIdx.x & 63;
    int slot = lane / 10;
    int t = lane % 10;
    bool active = slot < 6;
    int beg = rp[wid], end = rp[wid + 1];
    f32x4 acc = {0.f, 0.f, 0.f, 0.f};
    if (beg < end) {
        int last = end - 1;
        for (int base = beg; base < end; base += 18) {
            int i0 = base + slot, i1 = base + 6 + slot, i2 = base + 12 + slot;
            int i0c = (active && i0 < end) ? i0 : last;
            int i1c = (active && i1 < end) ? i1 : last;
            int i2c = (active && i2 < end) ? i2 : last;
            int u0 = col[i0c], u1 = col[i1c], u2 = col[i2c];
            float s0 = (active && i0 < end) ? (FIRST ? norm[u0] : 1.f) : 0.f;
            float s1 = (active && i1 < end) ? (FIRST ? norm[u1] : 1.f) : 0.f;
            float s2 = (active && i2 < end) ? (FIRST ? norm[u2] : 1.f) : 0.f;
            f32x4 x0 = hin[(size_t)u0 * 10 + t];
            f32x4 x1 = hin[(size_t)u1 * 10 + t];
            f32x4 x2 = hin[(size_t)u2 * 10 + t];
            acc.x += x0.x * s0; acc.y += x0.y * s0; acc.z += x0.z * s0; acc.w += x0.w * s0;
            acc.x += x1.x * s1; acc.y += x1.y * s1; acc.z += x1.z * s1; acc.w += x1.w * s1;
            acc.x += x2.x * s2; acc.y += x2.y * s2; acc.z += x2.z * s2; acc.w += x2.w * s2;
        }
    }
    f32x4 tot = acc;
    #pragma unroll
    for (int k = 1; k < 6; ++k) {
        int srcl = (lane % 10) + ((slot + k) % 6) * 10;
        tot.x += __shfl(acc.x, srcl);
        tot.y += __shfl(acc.y, srcl);
        tot.z += __shfl(acc.z, srcl);
        tot.w += __shfl(acc.w, srcl);
    }
    if (slot == 0) {
        float nv = norm[wid];
        float f = FIRST ? nv * nv : nv;
        f32x4 o = {tot.x * f, tot.y * f, tot.z * f, tot.w * f};
        if (BIAS) {
            f32x4 bv = ((const f32x4*)b3)[t];
            o.x += bv.x; o.y += bv.y; o.z += bv.z; o.w += bv.w;
        }
        __builtin_nontemporal_store(o, &hout[(size_t)wid * 10 + t]);
    }
}

// ------------------------- W fragment preparation --------------------------

__device__ __forceinline__ void wprep_one(const float* __restrict__ W,
                                          short* __restrict__ Wh,
                                          short* __restrict__ Wl,
                                          int ncols, int CF, int i) {
    int j = i & 7;
    int lane = (i >> 3) & 63;
    int f = i >> 9;
    int cf = f % CF, ks = f / CF;
    int k = ks * 32 + 8 * (lane >> 4) + j;
    int c = cf * 16 + (lane & 15);
    float v = (c < ncols) ? W[k * ncols + c] : 0.f;
    unsigned short h = f2bf(v);
    unsigned short l = f2bf(v - bf2f(h));
    Wh[i] = (short)h;
    Wl[i] = (short)l;
}

__global__ void __launch_bounds__(256) wprep_all(const float* __restrict__ W1,
                                                 const float* __restrict__ W2,
                                                 const float* __restrict__ W3,
                                                 short* __restrict__ W1h, short* __restrict__ W1l,
                                                 short* __restrict__ W2h, short* __restrict__ W2l,
                                                 short* __restrict__ W3h, short* __restrict__ W3l) {
    int i = blockIdx.x * blockDim.x + threadIdx.x;
    if (i < 16384) wprep_one(W1, W1h, W1l, 128, 8, i);
    else if (i < 32768) wprep_one(W2, W2h, W2l, 128, 8, i - 16384);
    else if (i < 38912) wprep_one(W3, W3h, W3l, 40, 3, i - 32768);
}

// ------------------------- split-bf16 MFMA GEMMs ---------------------------

template <int MODE>  // 0: int16-quantized out (+relu+bias, S/Sn); 1: split-bf16 out (+relu+bias)
__global__ void __launch_bounds__(256) gemm_mfma128(const unsigned short* __restrict__ Ahi,
                                                    const unsigned short* __restrict__ Alo,
                                                    const short8v* __restrict__ Wh,
                                                    const short8v* __restrict__ Wl,
                                                    const float* __restrict__ bias,
                                                    const float* __restrict__ norm,
                                                    unsigned short* __restrict__ Cq,
                                                    float* __restrict__ So,
                                                    float* __restrict__ Sno,
                                                    unsigned short* __restrict__ Chi,
                                                    unsigned short* __restrict__ Clo,
                                                    int n) {
    int lane = threadIdx.x & 63;
    int wid = threadIdx.x >> 6;
    int r0 = blockIdx.x * 64 + wid * 16;
    if (r0 >= n) return;
    int arow = r0 + (lane & 15);
    if (arow > n - 1) arow = n - 1;
    int kbase = 8 * (lane >> 4);
    f32x4 acc[8];
    #pragma unroll
    for (int i = 0; i < 8; ++i) acc[i] = (f32x4){0.f, 0.f, 0.f, 0.f};
    #pragma unroll
    for (int ks = 0; ks < 4; ++ks) {
        short8v ah = *(const short8v*)(Ahi + (size_t)arow * 128 + ks * 32 + kbase);
        short8v al = *(const short8v*)(Alo + (size_t)arow * 128 + ks * 32 + kbase);
        #pragma unroll
        for (int cf = 0; cf < 8; ++cf) {
            short8v bh = Wh[(ks * 8 + cf) * 64 + lane];
            short8v bl = Wl[(ks * 8 + cf) * 64 + lane];
            acc[cf] = __builtin_amdgcn_mfma_f32_16x16x32_bf16(ah, bh, acc[cf], 0, 0, 0);
            acc[cf] = __builtin_amdgcn_mfma_f32_16x16x32_bf16(al, bh, acc[cf], 0, 0, 0);
            acc[cf] = __builtin_amdgcn_mfma_f32_16x16x32_bf16(ah, bl, acc[cf], 0, 0, 0);
        }
    }
    int rbase = r0 + (lane >> 4) * 4;
    int c0 = lane & 15;
    float bc[8];
    #pragma unroll
    for (int cf = 0; cf < 8; ++cf) bc[cf] = bias[cf * 16 + c0];

    if (MODE == 0) {
        // per-row max (post-relu), reduced over the 16-lane row group
        float mq[4] = {0.f, 0.f, 0.f, 0.f};
        #pragma unroll
        for (int cf = 0; cf < 8; ++cf) {
            #pragma unroll
            for (int q = 0; q < 4; ++q)
                mq[q] = fmaxf(mq[q], fmaxf(acc[cf][q] + bc[cf], 0.f));
        }
        #pragma unroll
        for (int s = 1; s < 16; s <<= 1) {
            #pragma unroll
            for (int q = 0; q < 4; ++q) mq[q] = fmaxf(mq[q], __shfl_xor(mq[q], s));
        }
        float invq[4], svq[4];
        #pragma unroll
        for (int q = 0; q < 4; ++q) {
            float sraw = fmaxf(mq[q], 1e-30f);
            invq[q] = 32767.f / sraw;
            svq[q] = sraw * (1.f / 32767.f);
        }
        #pragma unroll
        for (int cf = 0; cf < 8; ++cf) {
            int colc = cf * 16 + c0;
            #pragma unroll
            for (int q = 0; q < 4; ++q) {
                int row = rbase + q;
                if (row >= n) continue;
                float v = fmaxf(acc[cf][q] + bc[cf], 0.f);
                int qi = (int)rintf(fminf(v * invq[q], 32767.f));  // v >= 0
                Cq[(size_t)row * 128 + colc] = (unsigned short)qi;
            }
        }
        if (c0 == 0) {
            #pragma unroll
            for (int q = 0; q < 4; ++q) {
                int row = rbase + q;
                if (row < n) { So[row] = svq[q]; Sno[row] = svq[q] * norm[row]; }
            }
        }
    } else {
        #pragma unroll
        for (int cf = 0; cf < 8; ++cf) {
            int colc = cf * 16 + c0;
            #pragma unroll
            for (int q = 0; q < 4; ++q) {
                int row = rbase + q;
                if (row >= n) continue;
                float v = fmaxf(acc[cf][q] + bc[cf], 0.f);
                unsigned short h = f2bf(v);
                unsigned short l = f2bf(v - bf2f(h));
                Chi[(size_t)row * 128 + colc] = h;
                Clo[(size_t)row * 128 + colc] = l;
            }
        }
    }
}

__global__ void __launch_bounds__(256) gemm_mfma40(const unsigned short* __restrict__ Ahi,
                                                   const unsigned short* __restrict__ Alo,
                                                   const short8v* __restrict__ Wh,
                                                   const short8v* __restrict__ Wl,
                                                   float* __restrict__ Cf, int n) {
    int lane = threadIdx.x & 63;
    int wid = threadIdx.x >> 6;
    int r0 = blockIdx.x * 64 + wid * 16;
    if (r0 >= n) return;
    int arow = r0 + (lane & 15);
    if (arow > n - 1) arow = n - 1;
    int kbase = 8 * (lane >> 4);
    f32x4 acc[3];
    #pragma unroll
    for (int i = 0; i < 3; ++i) acc[i] = (f32x4){0.f, 0.f, 0.f, 0.f};
    #pragma unroll
    for (int ks = 0; ks < 4; ++ks) {
        short8v ah = *(const short8v*)(Ahi + (size_t)arow * 128 + ks * 32 + kbase);
        short8v al = *(const short8v*)(Alo + (size_t)arow * 128 + ks * 32 + kbase);
        #pragma unroll
        for (int cf = 0; cf < 3; ++cf) {
            short8v bh = Wh[(ks * 3 + cf) * 64 + lane];
            short8v bl = Wl[(ks * 3 + cf) * 64 + lane];
            acc[cf] = __builtin_amdgcn_mfma_f32_16x16x32_bf16(ah, bh, acc[cf], 0, 0, 0);
            acc[cf] = __builtin_amdgcn_mfma_f32_16x16x32_bf16(al, bh, acc[cf], 0, 0, 0);
            acc[cf] = __builtin_amdgcn_mfma_f32_16x16x32_bf16(ah, bl, acc[cf], 0, 0, 0);
        }
    }
    int rbase = r0 + (lane >> 4) * 4;
    int c0 = lane & 15;
    #pragma unroll
    for (int cf = 0; cf < 3; ++cf) {
        int colc = cf * 16 + c0;
        if (colc >= 40) continue;
        #pragma unroll
        for (int q = 0; q < 4; ++q) {
            int row = rbase + q;
            if (row >= n) continue;
            Cf[(size_t)row * 40 + colc] = acc[cf][q];
        }
    }
}

// --------------------------------- launch ----------------------------------

extern "C" void kernel_launch(void* const* d_in, const int* in_sizes, int n_in,
                              void* d_out, int out_size, void* d_ws, size_t ws_size,
                              hipStream_t stream) {
    const float* features = (const float*)d_in[0];
    const int*   src      = (const int*)d_in[1];
    const int*   dst      = (const int*)d_in[2];
    const float* W1 = (const float*)d_in[3];
    const float* b1 = (const float*)d_in[4];
    const float* W2 = (const float*)d_in[5];
    const float* b2 = (const float*)d_in[6];
    const float* W3 = (const float*)d_in[7];
    const float* b3 = (const float*)d_in[8];
    float* out = (float*)d_out;

    const int N = in_sizes[0] / 128;
    const int E = in_sizes[1];

    char* ws = (char*)d_ws;
    size_t off = 0;
    auto alloc = [&](size_t bytes) -> void* {
        void* p = ws + off;
        off += (bytes + 511) & ~(size_t)511;
        return p;
    };
    // quantized feature buffers: [N][32] u32x2 (128 int16/row)
    u32x2* Xq  = (u32x2*)alloc((size_t)N * 32 * sizeof(u32x2));
    u32x2* F1q = (u32x2*)alloc((size_t)N * 32 * sizeof(u32x2));
    u32x2* F2q = (u32x2*)alloc((size_t)N * 32 * sizeof(u32x2));
    unsigned short* Hi = (unsigned short*)alloc((size_t)N * 128 * sizeof(unsigned short));
    unsigned short* Lo = (unsigned short*)alloc((size_t)N * 128 * sizeof(unsigned short));
    float* Sx  = (float*)alloc((size_t)N * sizeof(float));
    float* Snx = (float*)alloc((size_t)N * sizeof(float));
    float* S1  = (float*)alloc((size_t)N * sizeof(float));
    float* Sn1 = (float*)alloc((size_t)N * sizeof(float));
    float* S2  = (float*)alloc((size_t)N * sizeof(float));
    float* Sn2 = (float*)alloc((size_t)N * sizeof(float));
    int*   col    = (int*)alloc((size_t)E * sizeof(int));
    int*   deg    = (int*)alloc((size_t)N * sizeof(int));
    int*   rowptr = (int*)alloc((size_t)(N + 1) * sizeof(int));
    float* norm   = (float*)alloc((size_t)N * sizeof(float));
    int*   bsum   = (int*)alloc((size_t)(SBLK + 2) * sizeof(int));
    short* W1h = (short*)alloc(16384 * sizeof(short));
    short* W1l = (short*)alloc(16384 * sizeof(short));
    short* W2h = (short*)alloc(16384 * sizeof(short));
    short* W2l = (short*)alloc(16384 * sizeof(short));
    short* W3h = (short*)alloc(6144 * sizeof(short));
    short* W3l = (short*)alloc(6144 * sizeof(short));
    // aliases: rank -> Hi (dead until k2-L1); G40a -> F2q (dead after k1-L2),
    // G40b -> Xq (dead after k1-L1). 16 MB each fits the 25.6 MB slots.
    int*   rank = (int*)Hi;
    float* G40a = (float*)F2q;
    float* G40b = (float*)Xq;

    const int seg = (N + SBLK - 1) / SBLK;
    const int eblocks = (E + 255) / 256;

    // --- CSR build ---
    hipMemsetAsync(deg, 0, (size_t)N * sizeof(int), stream);
    deg_rank_kernel<<<eblocks, 256, 0, stream>>>(dst, deg, rank, E);
    scanA_kernel<<<SBLK, 256, 0, stream>>>(deg, rowptr, bsum, norm, N, seg);
    scanC_kernel<<<SBLK, 256, 0, stream>>>(rowptr, bsum, N, seg);
    fill_kernel<<<eblocks, 256, 0, stream>>>(src, dst, rowptr, rank, col, E);

    // --- W fragment prep + input quantization ---
    wprep_all<<<(38912 + 255) / 256, 256, 0, stream>>>(W1, W2, W3, W1h, W1l, W2h, W2l, W3h, W3l);
    {
        int waves2 = (N + 1) / 2;
        int xblocks = (waves2 * 64 + 255) / 256;
        xquant_kernel<<<xblocks, 256, 0, stream>>>((const float4*)features, norm, Xq, Sx, Snx, N);
    }

    const int spmm_blocks = (N * 64 + 255) / 256;  // one wave per node
    const int gemm_blocks = (N + 63) / 64;

    // layer 1: z = N^2 A N x ; y = N A z ; relu(y W1 + b1) -> quantized F2q
    spmm128_q<0><<<spmm_blocks, 256, 0, stream>>>(Xq, Snx, rowptr, col, norm,
                                                  F1q, S1, Sn1, nullptr, nullptr, N);
    spmm128_q<1><<<spmm_blocks, 256, 0, stream>>>(F1q, S1, rowptr, col, norm,
                                                  nullptr, nullptr, nullptr, (u32x2*)Hi, (u32x2*)Lo, N);
    gemm_mfma128<0><<<gemm_blocks, 256, 0, stream>>>(Hi, Lo, (const short8v*)W1h, (const short8v*)W1l,
                                                     b1, norm, (unsigned short*)F2q, S2, Sn2,
                                                     nullptr, nullptr, N);

    // layer 2: hops on quantized F2q; GEMM2 emits split-bf16 in-place (row-disjoint)
    spmm128_q<0><<<spmm_blocks, 256, 0, stream>>>(F2q, Sn2, rowptr, col, norm,
                                                  F1q, S1, Sn1, nullptr, nullptr, N);
    spmm128_q<1><<<spmm_blocks, 256, 0, stream>>>(F1q, S1, rowptr, col, norm,
                                                  nullptr, nullptr, nullptr, (u32x2*)Hi, (u32x2*)Lo, N);
    gemm_mfma128<1><<<gemm_blocks, 256, 0, stream>>>(Hi, Lo, (const short8v*)W2h, (const short8v*)W2l,
                                                     b2, norm, nullptr, nullptr, nullptr,
                                                     Hi, Lo, N);

    // layer 3 (reordered): project 128->40 first, then 2 hops at 40-wide, + b3
    gemm_mfma40<<<gemm_blocks, 256, 0, stream>>>(Hi, Lo, (const short8v*)W3h, (const short8v*)W3l, G40a, N);
    spmm40_kernel<1, 0><<<spmm_blocks, 256, 0, stream>>>((const f32x4*)G40a, (f32x4*)G40b, rowptr, col, norm, nullptr, N);
    spmm40_kernel<0, 1><<<spmm_blocks, 256, 0, stream>>>((const f32x4*)G40b, (f32x4*)out, rowptr, col, norm, b3, N);
}